// Round 13
// baseline (164.704 us; speedup 1.0000x reference)
//
#include <hip/hip_runtime.h>
#include <math.h>

#define EPSF 1.1920928955078125e-07f  // np.float32 eps

constexpr int B_ = 16, S_ = 8, CH = 3, K_ = 6;
constexpr int P_ = 128 * 128;  // pixels per image
constexpr int NCR = 2;         // moment chunks per image (8192 px each; r13: 4->2 to amortize epilogue)
constexpr int NCE = 32;        // estep chunks per image (512 px each)
constexpr int NF = 160;        // p1 stride: F 0..95, M2 96..105, Mss 106..153
constexpr int PW = 168;        // params stride: O 0..95, sinv 96..159 (8-stride), ldh 160

// REGISTER ALLOCATOR LAW (r3-r10): hipcc picks a per-kernel VGPR tier mostly
// ignoring launch_bounds; the 2nd arg can only LOWER the cap (causing spills).
// ONLY proven spill-free shapes for this code:
//   k_moments: 256 thr, (256,1), acc[46], 4-wide unrolled body   [r6, 144 us]
//   k_estep:   768 thr, (768,3), ~60 live                         [r6]
// r7-r12 measured: mega-fusion, 2-pass fusion, (256,4/5), 384-thr k-share,
// k-fastest ordering -- ALL regress. Do not restructure.

// bijective XCD swizzle (nwg % 8 == 0)
__device__ __forceinline__ int swz8(int bid, int nwg) {
  return (bid & 7) * (nwg >> 3) + (bid >> 3);
}
__device__ __forceinline__ float4 ld4(const float* p) { return *(const float4*)p; }
__device__ __forceinline__ void st4(float* p, float4 v) { *(float4*)p = v; }
__device__ __forceinline__ float dot4(float4 a, float4 b) {
  return a.x * b.x + a.y * b.y + a.z * b.z + a.w * b.w;
}
__device__ __forceinline__ float sum4(float4 a) { return a.x + a.y + a.z + a.w; }
__device__ __forceinline__ float4 mul4(float4 a, float4 b) {
  return make_float4(a.x * b.x, a.y * b.y, a.z * b.z, a.w * b.w);
}
__device__ __forceinline__ float4 dcompv(float4 s, float4 i0, float4 i1, float4 i2,
                                         float4 o) {
  float4 r;
  r.x = s.x - (o.x * i0.x + o.y * i1.x + o.z * i2.x + o.w);
  r.y = s.y - (o.x * i0.y + o.y * i1.y + o.z * i2.y + o.w);
  r.z = s.z - (o.x * i0.z + o.y * i1.z + o.z * i2.z + o.w);
  r.w = s.w - (o.x * i0.w + o.y * i1.w + o.z * i2.w + o.w);
  return r;
}
// 0.5-prescaled quadratic form (diag carries 0.5, offdiag carries 1.0)
__device__ __forceinline__ float quadv(float d0, float d1, float d2, float4 sA,
                                       float2 sB) {
  return sA.x * d0 * d0 + sA.y * d0 * d1 + sA.z * d0 * d2 + sA.w * d1 * d1 +
         sB.x * d1 * d2 + sB.y * d2 * d2;
}

// ------------------------------------------------------------------ 4x4 inverse
__device__ __forceinline__ void inv4(const float* Ain, float* out) {
  float a[4][8];
#pragma unroll
  for (int i = 0; i < 4; i++) {
#pragma unroll
    for (int j = 0; j < 4; j++) { a[i][j] = Ain[i * 4 + j]; a[i][4 + j] = (i == j) ? 1.f : 0.f; }
  }
#pragma unroll
  for (int c = 0; c < 4; c++) {
    float piv = 1.f / a[c][c];
#pragma unroll
    for (int j = 0; j < 8; j++) a[c][j] *= piv;
#pragma unroll
    for (int r = 0; r < 4; r++) {
      if (r != c) {
        float f = a[r][c];
#pragma unroll
        for (int j = 0; j < 8; j++) a[r][j] -= f * a[c][j];
      }
    }
  }
#pragma unroll
  for (int i = 0; i < 4; i++)
#pragma unroll
    for (int j = 0; j < 4; j++) out[i * 4 + j] = a[i][4 + j];
}

// ------------------------------------------------------------------ softmax (step 0)
__global__ __launch_bounds__(256) void k_softmax0(const float* __restrict__ pred,
                                                  float* __restrict__ gp) {
  int g = blockIdx.x * 256 + threadIdx.x;
  int u = g >> 14, p = g & (P_ - 1);
  size_t base = ((size_t)u * K_) * P_ + p;
  float l[K_];
  float mx = -1e30f;
#pragma unroll
  for (int k = 0; k < K_; k++) { l[k] = pred[base + (size_t)k * P_]; mx = fmaxf(mx, l[k]); }
  float s = 0.f;
#pragma unroll
  for (int k = 0; k < K_; k++) { l[k] = expf(l[k] - mx); s += l[k]; }
  float inv = 1.f / s;
#pragma unroll
  for (int k = 0; k < K_; k++) gp[base + (size_t)k * P_] = l[k] * inv + EPSF;
}

// ------------------------------------------------------------------ moments (r6-proven shape; 8192-px chunks)
// grid = B*K*4*NCR (768) x 256; one (u, k, s-pair, 8192-px chunk) per block.
// 8 main iterations with unroll-4 (same unrolled-body register pressure as the
// r6-proven 4-iter shape) -> epilogue share halves vs NCR=4.
__global__ __launch_bounds__(256, 1) void k_moments(const float* __restrict__ img,
                                                    const float* __restrict__ shf,
                                                    const float* __restrict__ gp,
                                                    float* __restrict__ p1) {
  __shared__ float red[46][17];
  int wg = swz8(blockIdx.x, B_ * K_ * 4 * NCR);
  int u = wg / (K_ * 4 * NCR);
  int r = wg % (K_ * 4 * NCR);
  int k = r >> 3, sq = (r >> 1) & 3, ch = r & 1;
  int tid = threadIdx.x, lane = tid & 63, w = tid >> 6;

  const float* imgu = img + (size_t)u * CH * P_;
  const float* shfu = shf + ((size_t)u * S_ + sq * 2) * CH * P_;
  const float* gpu = gp + (size_t)(u * K_ + k) * P_;

  float acc[46];
#pragma unroll
  for (int i = 0; i < 46; i++) acc[i] = 0.f;

#pragma unroll 4
  for (int it = 0; it < 8; it++) {
    int p = ch * 8192 + it * 1024 + tid * 4;
    float4 i0 = ld4(imgu + p);
    float4 i1 = ld4(imgu + P_ + p);
    float4 i2 = ld4(imgu + 2 * P_ + p);
    float4 g = ld4(gpu + p);
    float4 t0 = mul4(g, i0), t1 = mul4(g, i1), t2 = mul4(g, i2);
#pragma unroll
    for (int ls = 0; ls < 2; ls++) {
      float4 s0 = ld4(shfu + (ls * 3 + 0) * P_ + p);
      float4 s1 = ld4(shfu + (ls * 3 + 1) * P_ + p);
      float4 s2 = ld4(shfu + (ls * 3 + 2) * P_ + p);
      int fb = ls * 12;
      acc[fb + 0] += dot4(s0, t0); acc[fb + 1] += dot4(s0, t1);
      acc[fb + 2] += dot4(s0, t2); acc[fb + 3] += dot4(s0, g);
      acc[fb + 4] += dot4(s1, t0); acc[fb + 5] += dot4(s1, t1);
      acc[fb + 6] += dot4(s1, t2); acc[fb + 7] += dot4(s1, g);
      acc[fb + 8] += dot4(s2, t0); acc[fb + 9] += dot4(s2, t1);
      acc[fb + 10] += dot4(s2, t2); acc[fb + 11] += dot4(s2, g);
      float4 gs0 = mul4(g, s0), gs1 = mul4(g, s1), gs2 = mul4(g, s2);
      int mb = 24 + ls * 6;
      acc[mb + 0] += dot4(gs0, s0); acc[mb + 1] += dot4(gs0, s1);
      acc[mb + 2] += dot4(gs0, s2); acc[mb + 3] += dot4(gs1, s1);
      acc[mb + 4] += dot4(gs1, s2); acc[mb + 5] += dot4(gs2, s2);
    }
    if (sq == 0) {  // block-uniform: M2 only from quarter 0
      acc[36] += dot4(i0, t0); acc[37] += dot4(i1, t0); acc[38] += dot4(i2, t0);
      acc[39] += sum4(t0);
      acc[40] += dot4(i1, t1); acc[41] += dot4(i2, t1); acc[42] += sum4(t1);
      acc[43] += dot4(i2, t2); acc[44] += sum4(t2);
      acc[45] += sum4(g);
    }
  }
#pragma unroll
  for (int j = 0; j < 46; j++) {
    float v = acc[j];
    v += __shfl_xor(v, 1, 64);
    v += __shfl_xor(v, 2, 64);
    v += __shfl_xor(v, 4, 64);
    v += __shfl_xor(v, 8, 64);
    acc[j] = v;
  }
  if ((lane & 15) == 0) {
    int col = w * 4 + (lane >> 4);
#pragma unroll
    for (int j = 0; j < 46; j++) red[j][col] = acc[j];
  }
  __syncthreads();
  if (tid < 46 && (tid < 36 || sq == 0)) {
    float s = 0.f;
#pragma unroll
    for (int c = 0; c < 16; c++) s += red[tid][c];
    int off;
    if (tid < 24) off = (sq * 2 + tid / 12) * 12 + (tid % 12);
    else if (tid < 36) off = 106 + (sq * 2 + (tid - 24) / 6) * 6 + ((tid - 24) % 6);
    else off = 96 + (tid - 36);
    p1[((size_t)(u * K_ + k) * NCR + ch) * NF + off] = s;
  }
}

// ------------------------------------------------------------------ solve (per u)
// O_s = norm * F_s * inv(norm*M2 + eps I)
// sigma_s = pn*(Mss_s - F_s O_s^T - O_s F_s^T + O_s M2 O_s^T) + eps I   (exact)
__global__ __launch_bounds__(256) void k_solve(const float* __restrict__ p1,
                                               float* __restrict__ params) {
  __shared__ float sumL[K_][154];
  __shared__ float invAL[K_][16];
  __shared__ float OL[K_][96];
  __shared__ float normL[K_], pnL[K_];
  __shared__ float ldetL[K_ * S_];
  int u = blockIdx.x;
  int tid = threadIdx.x;

  for (int e = tid; e < K_ * 154; e += 256) {
    int k = e / 154, i = e % 154;
    const float* src = p1 + (size_t)(u * K_ + k) * NCR * NF + i;
    float s = 0.f;
#pragma unroll
    for (int c = 0; c < NCR; c++) s += src[c * NF];
    sumL[k][i] = s;
  }
  __syncthreads();
  if (tid < K_) {
    const float* m = &sumL[tid][96];
    float tr = m[0] + m[4] + m[7] + m[9];
    float nrm = 1.f / tr;
    normL[tid] = nrm;
    pnL[tid] = 1.f / m[9];
    const int sym[4][4] = {{0, 1, 2, 3}, {1, 4, 5, 6}, {2, 5, 7, 8}, {3, 6, 8, 9}};
    float A[16];
#pragma unroll
    for (int i = 0; i < 4; i++)
#pragma unroll
      for (int j = 0; j < 4; j++)
        A[i * 4 + j] = m[sym[i][j]] * nrm + ((i == j) ? EPSF : 0.f);
    inv4(A, invAL[tid]);
  }
  __syncthreads();
  for (int e = tid; e < K_ * 96; e += 256) {
    int k = e / 96, r = e % 96, sa = r >> 2, bc = r & 3;
    float v = 0.f;
#pragma unroll
    for (int c = 0; c < 4; c++) v += sumL[k][sa * 4 + c] * invAL[k][c * 4 + bc];
    v *= normL[k];
    OL[k][r] = v;
    params[(size_t)(u * K_ + k) * PW + r] = v;
  }
  __syncthreads();
  if (tid < K_ * S_) {
    int k = tid >> 3, s = tid & 7;
    const float* F = &sumL[k][s * 12];
    const float* O = &OL[k][s * 12];
    const float* M2 = &sumL[k][96];
    const float* Ms = &sumL[k][106 + s * 6];
    float pn = pnL[k];
    const int sym[4][4] = {{0, 1, 2, 3}, {1, 4, 5, 6}, {2, 5, 7, 8}, {3, 6, 8, 9}};
    float FO[9];
#pragma unroll
    for (int a = 0; a < 3; a++)
#pragma unroll
      for (int b = 0; b < 3; b++) {
        float v = 0.f;
#pragma unroll
        for (int c = 0; c < 4; c++) v += F[a * 4 + c] * O[b * 4 + c];
        FO[a * 3 + b] = v;
      }
    float W[12];
#pragma unroll
    for (int a = 0; a < 3; a++)
#pragma unroll
      for (int c = 0; c < 4; c++) {
        float v = 0.f;
#pragma unroll
        for (int d = 0; d < 4; d++) v += O[a * 4 + d] * M2[sym[d][c]];
        W[a * 4 + c] = v;
      }
    float OMO[6];
    {
      const int pa[6] = {0, 0, 0, 1, 1, 2}, pb[6] = {0, 1, 2, 1, 2, 2};
#pragma unroll
      for (int t = 0; t < 6; t++) {
        float v = 0.f;
#pragma unroll
        for (int c = 0; c < 4; c++) v += W[pa[t] * 4 + c] * O[pb[t] * 4 + c];
        OMO[t] = v;
      }
    }
    float a = pn * (Ms[0] - 2.f * FO[0] + OMO[0]) + EPSF;
    float b = pn * (Ms[1] - FO[1] - FO[3] + OMO[1]);
    float c = pn * (Ms[2] - FO[2] - FO[6] + OMO[2]);
    float d = pn * (Ms[3] - 2.f * FO[4] + OMO[3]) + EPSF;
    float e = pn * (Ms[4] - FO[5] - FO[7] + OMO[4]);
    float f = pn * (Ms[5] - 2.f * FO[8] + OMO[5]) + EPSF;
    float c00 = d * f - e * e, c01 = c * e - b * f, c02 = b * e - c * d;
    float det = a * c00 + b * c01 + c * c02;
    float id = 1.f / det;
    float* ps = params + (size_t)(u * K_ + k) * PW + 96 + s * 8;
    ps[0] = 0.5f * c00 * id;
    ps[1] = c01 * id;
    ps[2] = c02 * id;
    ps[3] = 0.5f * (a * f - c * c) * id;
    ps[4] = (c * b - a * e) * id;
    ps[5] = 0.5f * (a * d - b * b) * id;
    ldetL[tid] = logf(det);
  }
  __syncthreads();
  if (tid < K_) {
    float s = 0.f;
#pragma unroll
    for (int si = 0; si < S_; si++) s += ldetL[tid * S_ + si];
    params[(size_t)(u * K_ + tid) * PW + 160] = 0.5f * s;
  }
}

// ------------------------------------------------------------------ e-step (+ fused softmax)
// grid = B*NCE (512) x 768 = 12 waves = (6 k) x (2 s-halves); one 512-px chunk.
// LAST=0: gm -> in-LDS softmax -> gp (global); no out write (dead intermediate).
// LAST=1: write out only.
template <int LAST>
__global__ __launch_bounds__(768, 3) void k_estep(const float* __restrict__ img,
                                                  const float* __restrict__ shf,
                                                  const float* __restrict__ pred,
                                                  const float* __restrict__ params,
                                                  float* __restrict__ out,
                                                  float* __restrict__ gp) {
  __shared__ __align__(16) float pL[K_ * PW];
  __shared__ __align__(16) float qL[K_ * 512];
  __shared__ __align__(16) float gmL[K_][512];

  int wg = swz8(blockIdx.x, B_ * NCE);
  int u = wg >> 5, ch = wg & 31;
  int tid = threadIdx.x, lane = tid & 63, w = tid >> 6;
  int k = w >> 1, shalf = w & 1;

  for (int e = tid; e < K_ * PW; e += 768)
    pL[e] = params[(size_t)u * K_ * PW + e];
  __syncthreads();

  const float* ob = &pL[k * PW + shalf * 48];
  const float* sb = &pL[k * PW + 96 + shalf * 32];
  float ldh = pL[k * PW + 160];

  const float* imgu = img + (size_t)u * CH * P_;
  const float* shfu = shf + ((size_t)u * S_ + shalf * 4) * CH * P_;
  const float* predu = pred + (size_t)u * K_ * P_;
  int p0 = ch * 512 + lane * 4;
  int pxa = lane * 4, pxb = lane * 4 + 256;

  float4 i0a = ld4(imgu + p0),          i0b = ld4(imgu + p0 + 256);
  float4 i1a = ld4(imgu + P_ + p0),     i1b = ld4(imgu + P_ + p0 + 256);
  float4 i2a = ld4(imgu + 2 * P_ + p0), i2b = ld4(imgu + 2 * P_ + p0 + 256);
  float4 qa = make_float4(0.f, 0.f, 0.f, 0.f);
  float4 qb = make_float4(0.f, 0.f, 0.f, 0.f);
#pragma unroll
  for (int sl = 0; sl < 4; sl++) {
    float4 oA = ld4(ob + sl * 12 + 0);
    float4 oB = ld4(ob + sl * 12 + 4);
    float4 oC = ld4(ob + sl * 12 + 8);
    float4 sA = ld4(sb + sl * 8);
    float2 sB = *(const float2*)(sb + sl * 8 + 4);
    const float* s0 = shfu + (sl * 3 + 0) * P_;
    const float* s1 = shfu + (sl * 3 + 1) * P_;
    const float* s2 = shfu + (sl * 3 + 2) * P_;
    {
      float4 d0 = dcompv(ld4(s0 + p0), i0a, i1a, i2a, oA);
      float4 d1 = dcompv(ld4(s1 + p0), i0a, i1a, i2a, oB);
      float4 d2 = dcompv(ld4(s2 + p0), i0a, i1a, i2a, oC);
      qa.x += quadv(d0.x, d1.x, d2.x, sA, sB);
      qa.y += quadv(d0.y, d1.y, d2.y, sA, sB);
      qa.z += quadv(d0.z, d1.z, d2.z, sA, sB);
      qa.w += quadv(d0.w, d1.w, d2.w, sA, sB);
    }
    {
      float4 d0 = dcompv(ld4(s0 + p0 + 256), i0b, i1b, i2b, oA);
      float4 d1 = dcompv(ld4(s1 + p0 + 256), i0b, i1b, i2b, oB);
      float4 d2 = dcompv(ld4(s2 + p0 + 256), i0b, i1b, i2b, oC);
      qb.x += quadv(d0.x, d1.x, d2.x, sA, sB);
      qb.y += quadv(d0.y, d1.y, d2.y, sA, sB);
      qb.z += quadv(d0.z, d1.z, d2.z, sA, sB);
      qb.w += quadv(d0.w, d1.w, d2.w, sA, sB);
    }
  }
  if (shalf == 1) {
    st4(&qL[k * 512 + pxa], qa);
    st4(&qL[k * 512 + pxb], qb);
  }
  __syncthreads();
  if (shalf == 0) {
    float4 qha = ld4(&qL[k * 512 + pxa]);
    float4 qhb = ld4(&qL[k * 512 + pxb]);
    float4 g4a, g4b;
    g4a.x = -(qa.x + qha.x + ldh); g4a.y = -(qa.y + qha.y + ldh);
    g4a.z = -(qa.z + qha.z + ldh); g4a.w = -(qa.w + qha.w + ldh);
    g4b.x = -(qb.x + qhb.x + ldh); g4b.y = -(qb.y + qhb.y + ldh);
    g4b.z = -(qb.z + qhb.z + ldh); g4b.w = -(qb.w + qhb.w + ldh);
    if constexpr (LAST) {
      float* outu = out + (size_t)(u * K_ + k) * P_;
      st4(outu + ch * 512 + pxa, g4a);
      st4(outu + ch * 512 + pxb, g4b);
    } else {
      st4(&gmL[k][pxa], g4a);
      st4(&gmL[k][pxb], g4b);
    }
  }
  if constexpr (!LAST) {
    __syncthreads();
    if (tid < 512) {
      int p = ch * 512 + tid;
      float* gpu = gp + (size_t)u * K_ * P_;
      float l[K_];
      float mx = -1e30f;
#pragma unroll
      for (int k2 = 0; k2 < K_; k2++) {
        l[k2] = predu[(size_t)k2 * P_ + p] + gmL[k2][tid];
        mx = fmaxf(mx, l[k2]);
      }
      float ss = 0.f;
#pragma unroll
      for (int k2 = 0; k2 < K_; k2++) { l[k2] = expf(l[k2] - mx); ss += l[k2]; }
      float inv = 1.f / ss;
#pragma unroll
      for (int k2 = 0; k2 < K_; k2++) gpu[(size_t)k2 * P_ + p] = l[k2] * inv + EPSF;
    }
  }
}

// ------------------------------------------------------------------ launch
extern "C" void kernel_launch(void* const* d_in, const int* in_sizes, int n_in,
                              void* d_out, int out_size, void* d_ws, size_t ws_size,
                              hipStream_t stream) {
  const float* img = (const float*)d_in[0];   // [B,3,128,128]
  const float* shf = (const float*)d_in[1];   // [B,8,3,128,128]
  const float* pred = (const float*)d_in[2];  // [B,6,128,128]
  float* out = (float*)d_out;                 // [B,6,128,128]
  float* wsf = (float*)d_ws;
  float* gp = wsf;                                  // B*K*P
  float* p1 = gp + (size_t)B_ * K_ * P_;            // B*K*NCR*NF
  float* params = p1 + (size_t)B_ * K_ * NCR * NF;  // B*K*PW

  k_softmax0<<<(B_ * P_) / 256, 256, 0, stream>>>(pred, gp);
  for (int step = 0; step < 3; step++) {
    k_moments<<<B_ * K_ * 4 * NCR, 256, 0, stream>>>(img, shf, gp, p1);
    k_solve<<<B_, 256, 0, stream>>>(p1, params);
    if (step < 2)
      k_estep<0><<<B_ * NCE, 768, 0, stream>>>(img, shf, pred, params, nullptr, gp);
    else
      k_estep<1><<<B_ * NCE, 768, 0, stream>>>(img, shf, pred, params, out, nullptr);
  }
}

// Round 14
// 148.038 us; speedup vs baseline: 1.1126x; 1.1126x over previous
//
#include <hip/hip_runtime.h>
#include <math.h>

#define EPSF 1.1920928955078125e-07f  // np.float32 eps

constexpr int B_ = 16, S_ = 8, CH = 3, K_ = 6;
constexpr int P_ = 128 * 128;  // pixels per image
constexpr int NCR = 4;         // moment chunks per image (4096 px each) -- r13's NCR=2 regressed (latency streams)
constexpr int NCE = 32;        // estep chunks per image (512 px each)
constexpr int NF = 160;        // p1 stride: F 0..95, M2 96..105, Mss 106..153
constexpr int PW = 168;        // params stride: O 0..95, sinv 96..159 (8-stride), ldh 160

// FINAL CONFIG (r14 = r12 = r6 structure + dead-write elim; 144-149 us plateau).
// Measured-and-regressed alternatives: mega-fusion (r7/r8), launch_bounds
// min-occupancy >1 (r9: allocator CUTS VGPRs and spills), 384-thr k-sharing
// (r10), k-fastest ordering (r11), NCR=2 big chunks (r13). The plateau is a
// latency floor: no kernel is HBM- or VALU-saturated, and all regime-change
// levers measured worse.

// bijective XCD swizzle (nwg % 8 == 0)
__device__ __forceinline__ int swz8(int bid, int nwg) {
  return (bid & 7) * (nwg >> 3) + (bid >> 3);
}
__device__ __forceinline__ float4 ld4(const float* p) { return *(const float4*)p; }
__device__ __forceinline__ void st4(float* p, float4 v) { *(float4*)p = v; }
__device__ __forceinline__ float dot4(float4 a, float4 b) {
  return a.x * b.x + a.y * b.y + a.z * b.z + a.w * b.w;
}
__device__ __forceinline__ float sum4(float4 a) { return a.x + a.y + a.z + a.w; }
__device__ __forceinline__ float4 mul4(float4 a, float4 b) {
  return make_float4(a.x * b.x, a.y * b.y, a.z * b.z, a.w * b.w);
}
__device__ __forceinline__ float4 dcompv(float4 s, float4 i0, float4 i1, float4 i2,
                                         float4 o) {
  float4 r;
  r.x = s.x - (o.x * i0.x + o.y * i1.x + o.z * i2.x + o.w);
  r.y = s.y - (o.x * i0.y + o.y * i1.y + o.z * i2.y + o.w);
  r.z = s.z - (o.x * i0.z + o.y * i1.z + o.z * i2.z + o.w);
  r.w = s.w - (o.x * i0.w + o.y * i1.w + o.z * i2.w + o.w);
  return r;
}
// 0.5-prescaled quadratic form (diag carries 0.5, offdiag carries 1.0)
__device__ __forceinline__ float quadv(float d0, float d1, float d2, float4 sA,
                                       float2 sB) {
  return sA.x * d0 * d0 + sA.y * d0 * d1 + sA.z * d0 * d2 + sA.w * d1 * d1 +
         sB.x * d1 * d2 + sB.y * d2 * d2;
}

// ------------------------------------------------------------------ 4x4 inverse
__device__ __forceinline__ void inv4(const float* Ain, float* out) {
  float a[4][8];
#pragma unroll
  for (int i = 0; i < 4; i++) {
#pragma unroll
    for (int j = 0; j < 4; j++) { a[i][j] = Ain[i * 4 + j]; a[i][4 + j] = (i == j) ? 1.f : 0.f; }
  }
#pragma unroll
  for (int c = 0; c < 4; c++) {
    float piv = 1.f / a[c][c];
#pragma unroll
    for (int j = 0; j < 8; j++) a[c][j] *= piv;
#pragma unroll
    for (int r = 0; r < 4; r++) {
      if (r != c) {
        float f = a[r][c];
#pragma unroll
        for (int j = 0; j < 8; j++) a[r][j] -= f * a[c][j];
      }
    }
  }
#pragma unroll
  for (int i = 0; i < 4; i++)
#pragma unroll
    for (int j = 0; j < 4; j++) out[i * 4 + j] = a[i][4 + j];
}

// ------------------------------------------------------------------ softmax (step 0)
__global__ __launch_bounds__(256) void k_softmax0(const float* __restrict__ pred,
                                                  float* __restrict__ gp) {
  int g = blockIdx.x * 256 + threadIdx.x;
  int u = g >> 14, p = g & (P_ - 1);
  size_t base = ((size_t)u * K_) * P_ + p;
  float l[K_];
  float mx = -1e30f;
#pragma unroll
  for (int k = 0; k < K_; k++) { l[k] = pred[base + (size_t)k * P_]; mx = fmaxf(mx, l[k]); }
  float s = 0.f;
#pragma unroll
  for (int k = 0; k < K_; k++) { l[k] = expf(l[k] - mx); s += l[k]; }
  float inv = 1.f / s;
#pragma unroll
  for (int k = 0; k < K_; k++) gp[base + (size_t)k * P_] = l[k] * inv + EPSF;
}

// ------------------------------------------------------------------ moments (r6-proven shape AND ordering)
// grid = B*K*4*NCR (1536) x 256; one (u, k, s-pair, 4096-px chunk) per block.
__global__ __launch_bounds__(256, 1) void k_moments(const float* __restrict__ img,
                                                    const float* __restrict__ shf,
                                                    const float* __restrict__ gp,
                                                    float* __restrict__ p1) {
  __shared__ float red[46][17];
  int wg = swz8(blockIdx.x, B_ * K_ * 4 * NCR);
  int u = wg / 96;
  int r = wg % 96;
  int k = r >> 4, sq = (r >> 2) & 3, ch = r & 3;
  int tid = threadIdx.x, lane = tid & 63, w = tid >> 6;

  const float* imgu = img + (size_t)u * CH * P_;
  const float* shfu = shf + ((size_t)u * S_ + sq * 2) * CH * P_;
  const float* gpu = gp + (size_t)(u * K_ + k) * P_;

  float acc[46];
#pragma unroll
  for (int i = 0; i < 46; i++) acc[i] = 0.f;

#pragma unroll
  for (int it = 0; it < 4; it++) {
    int p = ch * 4096 + it * 1024 + tid * 4;
    float4 i0 = ld4(imgu + p);
    float4 i1 = ld4(imgu + P_ + p);
    float4 i2 = ld4(imgu + 2 * P_ + p);
    float4 g = ld4(gpu + p);
    float4 t0 = mul4(g, i0), t1 = mul4(g, i1), t2 = mul4(g, i2);
#pragma unroll
    for (int ls = 0; ls < 2; ls++) {
      float4 s0 = ld4(shfu + (ls * 3 + 0) * P_ + p);
      float4 s1 = ld4(shfu + (ls * 3 + 1) * P_ + p);
      float4 s2 = ld4(shfu + (ls * 3 + 2) * P_ + p);
      int fb = ls * 12;
      acc[fb + 0] += dot4(s0, t0); acc[fb + 1] += dot4(s0, t1);
      acc[fb + 2] += dot4(s0, t2); acc[fb + 3] += dot4(s0, g);
      acc[fb + 4] += dot4(s1, t0); acc[fb + 5] += dot4(s1, t1);
      acc[fb + 6] += dot4(s1, t2); acc[fb + 7] += dot4(s1, g);
      acc[fb + 8] += dot4(s2, t0); acc[fb + 9] += dot4(s2, t1);
      acc[fb + 10] += dot4(s2, t2); acc[fb + 11] += dot4(s2, g);
      float4 gs0 = mul4(g, s0), gs1 = mul4(g, s1), gs2 = mul4(g, s2);
      int mb = 24 + ls * 6;
      acc[mb + 0] += dot4(gs0, s0); acc[mb + 1] += dot4(gs0, s1);
      acc[mb + 2] += dot4(gs0, s2); acc[mb + 3] += dot4(gs1, s1);
      acc[mb + 4] += dot4(gs1, s2); acc[mb + 5] += dot4(gs2, s2);
    }
    if (sq == 0) {  // block-uniform: M2 only from quarter 0
      acc[36] += dot4(i0, t0); acc[37] += dot4(i1, t0); acc[38] += dot4(i2, t0);
      acc[39] += sum4(t0);
      acc[40] += dot4(i1, t1); acc[41] += dot4(i2, t1); acc[42] += sum4(t1);
      acc[43] += dot4(i2, t2); acc[44] += sum4(t2);
      acc[45] += sum4(g);
    }
  }
#pragma unroll
  for (int j = 0; j < 46; j++) {
    float v = acc[j];
    v += __shfl_xor(v, 1, 64);
    v += __shfl_xor(v, 2, 64);
    v += __shfl_xor(v, 4, 64);
    v += __shfl_xor(v, 8, 64);
    acc[j] = v;
  }
  if ((lane & 15) == 0) {
    int col = w * 4 + (lane >> 4);
#pragma unroll
    for (int j = 0; j < 46; j++) red[j][col] = acc[j];
  }
  __syncthreads();
  if (tid < 46 && (tid < 36 || sq == 0)) {
    float s = 0.f;
#pragma unroll
    for (int c = 0; c < 16; c++) s += red[tid][c];
    int off;
    if (tid < 24) off = (sq * 2 + tid / 12) * 12 + (tid % 12);
    else if (tid < 36) off = 106 + (sq * 2 + (tid - 24) / 6) * 6 + ((tid - 24) % 6);
    else off = 96 + (tid - 36);
    p1[((size_t)(u * K_ + k) * NCR + ch) * NF + off] = s;
  }
}

// ------------------------------------------------------------------ solve (per u)
// O_s = norm * F_s * inv(norm*M2 + eps I)
// sigma_s = pn*(Mss_s - F_s O_s^T - O_s F_s^T + O_s M2 O_s^T) + eps I   (exact)
__global__ __launch_bounds__(256) void k_solve(const float* __restrict__ p1,
                                               float* __restrict__ params) {
  __shared__ float sumL[K_][154];
  __shared__ float invAL[K_][16];
  __shared__ float OL[K_][96];
  __shared__ float normL[K_], pnL[K_];
  __shared__ float ldetL[K_ * S_];
  int u = blockIdx.x;
  int tid = threadIdx.x;

  for (int e = tid; e < K_ * 154; e += 256) {
    int k = e / 154, i = e % 154;
    const float* src = p1 + (size_t)(u * K_ + k) * NCR * NF + i;
    float s = 0.f;
#pragma unroll
    for (int c = 0; c < NCR; c++) s += src[c * NF];
    sumL[k][i] = s;
  }
  __syncthreads();
  if (tid < K_) {
    const float* m = &sumL[tid][96];
    float tr = m[0] + m[4] + m[7] + m[9];
    float nrm = 1.f / tr;
    normL[tid] = nrm;
    pnL[tid] = 1.f / m[9];
    const int sym[4][4] = {{0, 1, 2, 3}, {1, 4, 5, 6}, {2, 5, 7, 8}, {3, 6, 8, 9}};
    float A[16];
#pragma unroll
    for (int i = 0; i < 4; i++)
#pragma unroll
      for (int j = 0; j < 4; j++)
        A[i * 4 + j] = m[sym[i][j]] * nrm + ((i == j) ? EPSF : 0.f);
    inv4(A, invAL[tid]);
  }
  __syncthreads();
  for (int e = tid; e < K_ * 96; e += 256) {
    int k = e / 96, r = e % 96, sa = r >> 2, bc = r & 3;
    float v = 0.f;
#pragma unroll
    for (int c = 0; c < 4; c++) v += sumL[k][sa * 4 + c] * invAL[k][c * 4 + bc];
    v *= normL[k];
    OL[k][r] = v;
    params[(size_t)(u * K_ + k) * PW + r] = v;
  }
  __syncthreads();
  if (tid < K_ * S_) {
    int k = tid >> 3, s = tid & 7;
    const float* F = &sumL[k][s * 12];
    const float* O = &OL[k][s * 12];
    const float* M2 = &sumL[k][96];
    const float* Ms = &sumL[k][106 + s * 6];
    float pn = pnL[k];
    const int sym[4][4] = {{0, 1, 2, 3}, {1, 4, 5, 6}, {2, 5, 7, 8}, {3, 6, 8, 9}};
    float FO[9];
#pragma unroll
    for (int a = 0; a < 3; a++)
#pragma unroll
      for (int b = 0; b < 3; b++) {
        float v = 0.f;
#pragma unroll
        for (int c = 0; c < 4; c++) v += F[a * 4 + c] * O[b * 4 + c];
        FO[a * 3 + b] = v;
      }
    float W[12];
#pragma unroll
    for (int a = 0; a < 3; a++)
#pragma unroll
      for (int c = 0; c < 4; c++) {
        float v = 0.f;
#pragma unroll
        for (int d = 0; d < 4; d++) v += O[a * 4 + d] * M2[sym[d][c]];
        W[a * 4 + c] = v;
      }
    float OMO[6];
    {
      const int pa[6] = {0, 0, 0, 1, 1, 2}, pb[6] = {0, 1, 2, 1, 2, 2};
#pragma unroll
      for (int t = 0; t < 6; t++) {
        float v = 0.f;
#pragma unroll
        for (int c = 0; c < 4; c++) v += W[pa[t] * 4 + c] * O[pb[t] * 4 + c];
        OMO[t] = v;
      }
    }
    float a = pn * (Ms[0] - 2.f * FO[0] + OMO[0]) + EPSF;
    float b = pn * (Ms[1] - FO[1] - FO[3] + OMO[1]);
    float c = pn * (Ms[2] - FO[2] - FO[6] + OMO[2]);
    float d = pn * (Ms[3] - 2.f * FO[4] + OMO[3]) + EPSF;
    float e = pn * (Ms[4] - FO[5] - FO[7] + OMO[4]);
    float f = pn * (Ms[5] - 2.f * FO[8] + OMO[5]) + EPSF;
    float c00 = d * f - e * e, c01 = c * e - b * f, c02 = b * e - c * d;
    float det = a * c00 + b * c01 + c * c02;
    float id = 1.f / det;
    float* ps = params + (size_t)(u * K_ + k) * PW + 96 + s * 8;
    ps[0] = 0.5f * c00 * id;
    ps[1] = c01 * id;
    ps[2] = c02 * id;
    ps[3] = 0.5f * (a * f - c * c) * id;
    ps[4] = (c * b - a * e) * id;
    ps[5] = 0.5f * (a * d - b * b) * id;
    ldetL[tid] = logf(det);
  }
  __syncthreads();
  if (tid < K_) {
    float s = 0.f;
#pragma unroll
    for (int si = 0; si < S_; si++) s += ldetL[tid * S_ + si];
    params[(size_t)(u * K_ + tid) * PW + 160] = 0.5f * s;
  }
}

// ------------------------------------------------------------------ e-step (+ fused softmax)
// grid = B*NCE (512) x 768 = 12 waves = (6 k) x (2 s-halves); one 512-px chunk.
// LAST=0: gm -> in-LDS softmax -> gp (global); no out write (dead intermediate).
// LAST=1: write out only.
template <int LAST>
__global__ __launch_bounds__(768, 3) void k_estep(const float* __restrict__ img,
                                                  const float* __restrict__ shf,
                                                  const float* __restrict__ pred,
                                                  const float* __restrict__ params,
                                                  float* __restrict__ out,
                                                  float* __restrict__ gp) {
  __shared__ __align__(16) float pL[K_ * PW];
  __shared__ __align__(16) float qL[K_ * 512];
  __shared__ __align__(16) float gmL[K_][512];

  int wg = swz8(blockIdx.x, B_ * NCE);
  int u = wg >> 5, ch = wg & 31;
  int tid = threadIdx.x, lane = tid & 63, w = tid >> 6;
  int k = w >> 1, shalf = w & 1;

  for (int e = tid; e < K_ * PW; e += 768)
    pL[e] = params[(size_t)u * K_ * PW + e];
  __syncthreads();

  const float* ob = &pL[k * PW + shalf * 48];
  const float* sb = &pL[k * PW + 96 + shalf * 32];
  float ldh = pL[k * PW + 160];

  const float* imgu = img + (size_t)u * CH * P_;
  const float* shfu = shf + ((size_t)u * S_ + shalf * 4) * CH * P_;
  const float* predu = pred + (size_t)u * K_ * P_;
  int p0 = ch * 512 + lane * 4;
  int pxa = lane * 4, pxb = lane * 4 + 256;

  float4 i0a = ld4(imgu + p0),          i0b = ld4(imgu + p0 + 256);
  float4 i1a = ld4(imgu + P_ + p0),     i1b = ld4(imgu + P_ + p0 + 256);
  float4 i2a = ld4(imgu + 2 * P_ + p0), i2b = ld4(imgu + 2 * P_ + p0 + 256);
  float4 qa = make_float4(0.f, 0.f, 0.f, 0.f);
  float4 qb = make_float4(0.f, 0.f, 0.f, 0.f);
#pragma unroll
  for (int sl = 0; sl < 4; sl++) {
    float4 oA = ld4(ob + sl * 12 + 0);
    float4 oB = ld4(ob + sl * 12 + 4);
    float4 oC = ld4(ob + sl * 12 + 8);
    float4 sA = ld4(sb + sl * 8);
    float2 sB = *(const float2*)(sb + sl * 8 + 4);
    const float* s0 = shfu + (sl * 3 + 0) * P_;
    const float* s1 = shfu + (sl * 3 + 1) * P_;
    const float* s2 = shfu + (sl * 3 + 2) * P_;
    {
      float4 d0 = dcompv(ld4(s0 + p0), i0a, i1a, i2a, oA);
      float4 d1 = dcompv(ld4(s1 + p0), i0a, i1a, i2a, oB);
      float4 d2 = dcompv(ld4(s2 + p0), i0a, i1a, i2a, oC);
      qa.x += quadv(d0.x, d1.x, d2.x, sA, sB);
      qa.y += quadv(d0.y, d1.y, d2.y, sA, sB);
      qa.z += quadv(d0.z, d1.z, d2.z, sA, sB);
      qa.w += quadv(d0.w, d1.w, d2.w, sA, sB);
    }
    {
      float4 d0 = dcompv(ld4(s0 + p0 + 256), i0b, i1b, i2b, oA);
      float4 d1 = dcompv(ld4(s1 + p0 + 256), i0b, i1b, i2b, oB);
      float4 d2 = dcompv(ld4(s2 + p0 + 256), i0b, i1b, i2b, oC);
      qb.x += quadv(d0.x, d1.x, d2.x, sA, sB);
      qb.y += quadv(d0.y, d1.y, d2.y, sA, sB);
      qb.z += quadv(d0.z, d1.z, d2.z, sA, sB);
      qb.w += quadv(d0.w, d1.w, d2.w, sA, sB);
    }
  }
  if (shalf == 1) {
    st4(&qL[k * 512 + pxa], qa);
    st4(&qL[k * 512 + pxb], qb);
  }
  __syncthreads();
  if (shalf == 0) {
    float4 qha = ld4(&qL[k * 512 + pxa]);
    float4 qhb = ld4(&qL[k * 512 + pxb]);
    float4 g4a, g4b;
    g4a.x = -(qa.x + qha.x + ldh); g4a.y = -(qa.y + qha.y + ldh);
    g4a.z = -(qa.z + qha.z + ldh); g4a.w = -(qa.w + qha.w + ldh);
    g4b.x = -(qb.x + qhb.x + ldh); g4b.y = -(qb.y + qhb.y + ldh);
    g4b.z = -(qb.z + qhb.z + ldh); g4b.w = -(qb.w + qhb.w + ldh);
    if constexpr (LAST) {
      float* outu = out + (size_t)(u * K_ + k) * P_;
      st4(outu + ch * 512 + pxa, g4a);
      st4(outu + ch * 512 + pxb, g4b);
    } else {
      st4(&gmL[k][pxa], g4a);
      st4(&gmL[k][pxb], g4b);
    }
  }
  if constexpr (!LAST) {
    __syncthreads();
    if (tid < 512) {
      int p = ch * 512 + tid;
      float* gpu = gp + (size_t)u * K_ * P_;
      float l[K_];
      float mx = -1e30f;
#pragma unroll
      for (int k2 = 0; k2 < K_; k2++) {
        l[k2] = predu[(size_t)k2 * P_ + p] + gmL[k2][tid];
        mx = fmaxf(mx, l[k2]);
      }
      float ss = 0.f;
#pragma unroll
      for (int k2 = 0; k2 < K_; k2++) { l[k2] = expf(l[k2] - mx); ss += l[k2]; }
      float inv = 1.f / ss;
#pragma unroll
      for (int k2 = 0; k2 < K_; k2++) gpu[(size_t)k2 * P_ + p] = l[k2] * inv + EPSF;
    }
  }
}

// ------------------------------------------------------------------ launch
extern "C" void kernel_launch(void* const* d_in, const int* in_sizes, int n_in,
                              void* d_out, int out_size, void* d_ws, size_t ws_size,
                              hipStream_t stream) {
  const float* img = (const float*)d_in[0];   // [B,3,128,128]
  const float* shf = (const float*)d_in[1];   // [B,8,3,128,128]
  const float* pred = (const float*)d_in[2];  // [B,6,128,128]
  float* out = (float*)d_out;                 // [B,6,128,128]
  float* wsf = (float*)d_ws;
  float* gp = wsf;                                  // B*K*P
  float* p1 = gp + (size_t)B_ * K_ * P_;            // B*K*NCR*NF
  float* params = p1 + (size_t)B_ * K_ * NCR * NF;  // B*K*PW

  k_softmax0<<<(B_ * P_) / 256, 256, 0, stream>>>(pred, gp);
  for (int step = 0; step < 3; step++) {
    k_moments<<<B_ * K_ * 4 * NCR, 256, 0, stream>>>(img, shf, gp, p1);
    k_solve<<<B_, 256, 0, stream>>>(p1, params);
    if (step < 2)
      k_estep<0><<<B_ * NCE, 768, 0, stream>>>(img, shf, pred, params, nullptr, gp);
    else
      k_estep<1><<<B_ * NCE, 768, 0, stream>>>(img, shf, pred, params, out, nullptr);
  }
}